// Round 11
// baseline (523.606 us; speedup 1.0000x reference)
//
#include <hip/hip_runtime.h>

#define T_TOKENS 4096   // B*S
#define DIM      1024   // D
#define NEXP     8      // E
#define FDIM     4096   // F
#define NASSIGN  8192   // T_TOKENS * K
#define PADROWS  8448

typedef __bf16 bf16x8 __attribute__((ext_vector_type(8)));
typedef float  f32x4  __attribute__((ext_vector_type(4)));
typedef short  short4v __attribute__((ext_vector_type(4)));
typedef short  short8v __attribute__((ext_vector_type(8)));
typedef unsigned short us8 __attribute__((ext_vector_type(8)));

__device__ __forceinline__ unsigned short cvt_bf16(float f) {
  return __builtin_bit_cast(unsigned short, (__bf16)f);   // HW cvt (RNE)
}
__device__ __forceinline__ float b2f(unsigned short h) {
  unsigned u = ((unsigned)h) << 16;
  return __builtin_bit_cast(float, u);
}
__device__ __forceinline__ void gload_lds16(const void* g, void* l) {
  __builtin_amdgcn_global_load_lds(
      (const __attribute__((address_space(1))) void*)g,
      (__attribute__((address_space(3))) void*)l, 16, 0, 0);
}

// paired hardware-transpose LDS reads: lo = k+0..3, hi = k+4..7 (OFF, OFF+1024 bytes)
template <int OFF>
__device__ __forceinline__ void tr2(short4v& lo, short4v& hi, unsigned addr) {
  asm volatile("ds_read_b64_tr_b16 %0, %2 offset:%c3\n\t"
               "ds_read_b64_tr_b16 %1, %2 offset:%c4"
               : "=&v"(lo), "=&v"(hi)
               : "v"(addr), "i"(OFF), "i"(OFF + 1024));
}

// ---------------- router ----------------
__global__ void router_kernel(const float* __restrict__ x, const float* __restrict__ rw,
                              const float* __restrict__ rb, int* __restrict__ tidx,
                              float* __restrict__ tw, int* __restrict__ counts) {
  int gid = blockIdx.x * blockDim.x + threadIdx.x;
  int t = gid >> 6;
  int lane = threadIdx.x & 63;
  if (t >= T_TOKENS) return;
  const float* xr = x + (size_t)t * DIM;
  float acc[NEXP];
#pragma unroll
  for (int e = 0; e < NEXP; ++e) acc[e] = 0.f;
  for (int d = lane; d < DIM; d += 64) {
    float xv = xr[d];
    const float* r = rw + (size_t)d * NEXP;
#pragma unroll
    for (int e = 0; e < NEXP; ++e) acc[e] += xv * r[e];
  }
#pragma unroll
  for (int e = 0; e < NEXP; ++e) {
#pragma unroll
    for (int off = 32; off > 0; off >>= 1) acc[e] += __shfl_xor(acc[e], off);
  }
  if (lane == 0) {
    float lg[NEXP], m = -1e30f;
#pragma unroll
    for (int e = 0; e < NEXP; ++e) { lg[e] = acc[e] + rb[e]; m = fmaxf(m, lg[e]); }
    float p[NEXP], Z = 0.f;
#pragma unroll
    for (int e = 0; e < NEXP; ++e) { p[e] = expf(lg[e] - m); Z += p[e]; }
    int i0 = 0;
#pragma unroll
    for (int e = 1; e < NEXP; ++e) if (p[e] > p[i0]) i0 = e;
    int i1 = (i0 == 0) ? 1 : 0;
#pragma unroll
    for (int e = 0; e < NEXP; ++e) if (e != i0 && p[e] > p[i1]) i1 = e;
    float q0 = p[i0] / Z, q1 = p[i1] / Z;
    float s = q0 + q1 + 1e-8f;
    tidx[t * 2] = i0; tidx[t * 2 + 1] = i1;
    tw[t * 2] = q0 / s; tw[t * 2 + 1] = q1 / s;
    atomicAdd(&counts[i0], 1); atomicAdd(&counts[i1], 1);
  }
}

// ---------------- scan (parallelized tlist writes) ----------------
__global__ void scan_kernel(const int* __restrict__ counts, int* __restrict__ offsets,
                            int* __restrict__ cursors, int* __restrict__ ntiles_p,
                            int* __restrict__ tlist) {
  __shared__ int mts[NEXP], tstart[NEXP];
  int l = threadIdx.x;
  if (l == 0) {
    int s = 0, t = 0;
    for (int e = 0; e < NEXP; ++e) {
      offsets[e] = s; cursors[e] = s;
      int m = (counts[e] + 127) >> 7;
      mts[e] = m; tstart[e] = t;
      s += counts[e]; t += m;
    }
    offsets[NEXP] = s;
    *ntiles_p = t;
  }
  __syncthreads();
  if (l < NEXP) {
    int t0 = tstart[l], m = mts[l];
    for (int mt = 0; mt < m; ++mt) tlist[t0 + mt] = (l << 8) | mt;
  }
}

// ---------------- gather x rows (fp32 -> bf16) ----------------
__global__ void gather_kernel(const float* __restrict__ x, const int* __restrict__ tidx,
                              int* __restrict__ cursors, int* __restrict__ tslot,
                              unsigned short* __restrict__ Xg) {
  int aid = (blockIdx.x * blockDim.x + threadIdx.x) >> 6;
  int lane = threadIdx.x & 63;
  if (aid >= NASSIGN) return;
  int t = aid >> 1, k = aid & 1;
  int e = tidx[t * 2 + k];
  int slot = 0;
  if (lane == 0) {
    slot = atomicAdd(&cursors[e], 1);
    tslot[t * 2 + k] = slot;
  }
  slot = __shfl(slot, 0);
  const float4* xr = (const float4*)(x + (size_t)t * DIM);
  ushort4* dst = (ushort4*)(Xg + (size_t)slot * DIM);
#pragma unroll
  for (int i = 0; i < 4; ++i) {
    int idx = i * 64 + lane;
    float4 v = xr[idx];
    ushort4 o;
    o.x = cvt_bf16(v.x); o.y = cvt_bf16(v.y); o.z = cvt_bf16(v.z); o.w = cvt_bf16(v.w);
    dst[idx] = o;
  }
}

// ---------------- streaming fp32 -> bf16 convert (layout preserved, coalesced) ----------
__global__ void convert_bf16(const float* __restrict__ src, unsigned short* __restrict__ dst,
                             int n8) {
  int stride = gridDim.x * blockDim.x;
  for (int i = blockIdx.x * blockDim.x + threadIdx.x; i < n8; i += stride) {
    float4 v0 = ((const float4*)src)[i * 2];
    float4 v1 = ((const float4*)src)[i * 2 + 1];
    us8 o;
    o[0] = cvt_bf16(v0.x); o[1] = cvt_bf16(v0.y); o[2] = cvt_bf16(v0.z); o[3] = cvt_bf16(v0.w);
    o[4] = cvt_bf16(v1.x); o[5] = cvt_bf16(v1.y); o[6] = cvt_bf16(v1.z); o[7] = cvt_bf16(v1.w);
    ((us8*)dst)[i] = o;
  }
}

// ---------------- 128x128 grouped GEMM, B consumed K-MAJOR via hardware tr_read -------
// A: [slots][KTOT] bf16 (K-major, ds_read_b128 + XOR swizzle -- unchanged from R10).
// Bc: [E][KTOT][NN] bf16 (natural converted weights, k rows, n cols -- NO transpose pass).
// B LDS: [kg 16][ng 8] regions of [4k][16n] subtiles (128B each). Stage (w,i): kg=w*4+i,
//   lane l -> global (k = kg*4 + ((l>>1)&3), n = (l>>3)*16 + (l&1)*8): 4 x 256B segments.
// Read: tr2 pairs; group base = vb2 + kk*8192 + j*128 (+1024) -> lane holds
//   B[n = wn*64 + j*16 + (l&15)][k = kk*32 + (l>>4)*8 + 0..7]. Algebra verified vs R9-pass.
#define COMPUTE_KK(KK)                                                                   \
  {                                                                                      \
    short4v lo[4], hi[4];                                                                \
    tr2<(KK) * 8192 + 0>(lo[0], hi[0], vb2);                                             \
    tr2<(KK) * 8192 + 128>(lo[1], hi[1], vb2);                                           \
    tr2<(KK) * 8192 + 256>(lo[2], hi[2], vb2);                                           \
    tr2<(KK) * 8192 + 384>(lo[3], hi[3], vb2);                                           \
    int cb = ((KK) * 64 + (l >> 4) * 16) ^ ((l & 7) << 4);                               \
    bf16x8 af[4];                                                                        \
    _Pragma("unroll") for (int i = 0; i < 4; ++i) {                                      \
      int row = wm * 64 + i * 16 + (l & 15);                                             \
      af[i] = *(const bf16x8*)((const char*)&As[0] + row * 128 + cb);                    \
    }                                                                                    \
    asm volatile("s_waitcnt lgkmcnt(0)" ::: "memory");                                   \
    __builtin_amdgcn_sched_barrier(0);                                                   \
    _Pragma("unroll") for (int j = 0; j < 4; ++j) {                                      \
      bf16x8 bfr = __builtin_bit_cast(                                                   \
          bf16x8, (short8v)__builtin_shufflevector(lo[j], hi[j], 0, 1, 2, 3, 4, 5, 6, 7)); \
      _Pragma("unroll") for (int i = 0; i < 4; ++i)                                      \
        acc[i][j] = __builtin_amdgcn_mfma_f32_16x16x32_bf16(af[i], bfr, acc[i][j], 0, 0, 0); \
    }                                                                                    \
  }

template <bool GELU, int KTOT, int NN, bool PARTIAL, bool SPLITK, int SPAN, int NCH>
__global__ __launch_bounds__(256, 4) void ffn_gemm128(
    const unsigned short* __restrict__ A, const unsigned short* __restrict__ Bc,
    const float* __restrict__ bias, void* __restrict__ OutP,
    const int* __restrict__ offsets, const int* __restrict__ ntiles_p,
    const int* __restrict__ tlist) {
  int gx = gridDim.x;
  int orig = blockIdx.y * gx + blockIdx.x;
  // grouped-aware XCD supertile: XCD x owns CONTIGUOUS tlist entries [9x, 9x+9)
  int xcd   = orig & 7;
  int local = orig >> 3;
  int nc  = local / (NCH * 9);
  int rem = local - nc * (NCH * 9);
  int m   = rem / NCH;
  int nn  = rem - m * NCH;
  int xb  = nc * NCH + nn;
  int yb  = xcd * 9 + m;

  int kh = 0;
  if (SPLITK) { kh = xb & 1; xb >>= 1; }

  int ntiles = *ntiles_p;
  if (yb >= ntiles) return;
  int ent = tlist[yb];
  int e = ent >> 8, mt = ent & 255;
  int off = offsets[e];
  int n_e = offsets[e + 1] - off;
  int row0 = off + mt * 128;
  if (mt * 128 >= n_e) return;
  int rows_valid = n_e - mt * 128; if (rows_valid > 128) rows_valid = 128;
  int n0 = xb * 128;
  int kbase = kh * SPAN;

  __shared__ unsigned short As[128 * 64];
  __shared__ unsigned short Bs[64 * 128];

  int tid = threadIdx.x, w = tid >> 6, l = tid & 63;
  int wm = w >> 1, wn = w & 1;

  f32x4 acc[4][4] = {};

  const unsigned short* Ab = A + (size_t)row0 * KTOT;
  const unsigned short* Bg = Bc + (size_t)e * KTOT * NN + n0;
  int srow = l >> 3;                     // A: row within 8-row group
  int scol = ((l & 7) ^ (l >> 3)) * 8;   // A: pre-swizzled source chunk (shorts)
  int kr   = (l >> 1) & 3;               // B: k row within 4-row subtile
  int ncol = ((l >> 3) << 4) + ((l & 1) << 3);   // B: n col (16B chunk)

  unsigned bsOff = (unsigned)(uintptr_t)(__attribute__((address_space(3))) unsigned short*)Bs;
  unsigned vb2 = bsOff + ((unsigned)(l >> 4) << 11) + ((unsigned)(l & 15) << 3)
               + ((unsigned)wn << 9);

#pragma unroll 1
  for (int k0 = kbase; k0 < kbase + SPAN; k0 += 64) {
#pragma unroll
    for (int i = 0; i < 4; ++i) {
      int R = w * 32 + i * 8;
      gload_lds16(Ab + (size_t)(R + srow) * KTOT + k0 + scol, &As[R * 64]);
      int kg = w * 4 + i;
      gload_lds16(Bg + (size_t)(k0 + kg * 4 + kr) * NN + ncol, &Bs[kg * 512]);
    }
    __syncthreads();   // vmcnt(0) drain; resident blocks overlap each other
    COMPUTE_KK(0)
    COMPUTE_KK(1)
    __syncthreads();
  }

  int cr = (l >> 4) * 4, cc = l & 15;
#pragma unroll
  for (int i = 0; i < 4; ++i) {
#pragma unroll
    for (int r = 0; r < 4; ++r) {
      int rl = wm * 64 + i * 16 + cr + r;
      if (rl < rows_valid) {
#pragma unroll
        for (int j = 0; j < 4; ++j) {
          int col = n0 + wn * 64 + j * 16 + cc;
          unsigned short* Oh = (unsigned short*)OutP;
          if (PARTIAL) {
            Oh[((size_t)(kh * PADROWS) + row0 + rl) * NN + col] = cvt_bf16(acc[i][j][r]);
          } else {
            float v = acc[i][j][r] + bias[(size_t)e * NN + col];
            if (GELU) v = 0.5f * v * (1.0f + erff(v * 0.70710678118654752f));
            Oh[(size_t)(row0 + rl) * NN + col] = cvt_bf16(v);
          }
        }
      }
    }
  }
}

// ---------------- combine: out = x + sum_k w_k*(EOp0[s_k]+EOp1[s_k]+b2[e_k]) ----------------
__global__ void combine_kernel(const float* __restrict__ x, const unsigned short* __restrict__ EOp,
                               const int* __restrict__ tslot, const int* __restrict__ tidx,
                               const float* __restrict__ tw, const float* __restrict__ b2,
                               float* __restrict__ out) {
  int t = blockIdx.x;
  int s0 = tslot[t * 2], s1 = tslot[t * 2 + 1];
  int e0 = tidx[t * 2], e1 = tidx[t * 2 + 1];
  float w0 = tw[t * 2], w1 = tw[t * 2 + 1];
  int i = threadIdx.x;
  float4 xv = ((const float4*)(x + (size_t)t * DIM))[i];
  ushort4 a0 = ((const ushort4*)(EOp + (size_t)s0 * DIM))[i];
  ushort4 a1 = ((const ushort4*)(EOp + ((size_t)PADROWS + s0) * DIM))[i];
  ushort4 c0 = ((const ushort4*)(EOp + (size_t)s1 * DIM))[i];
  ushort4 c1 = ((const ushort4*)(EOp + ((size_t)PADROWS + s1) * DIM))[i];
  float4 b0 = ((const float4*)(b2 + (size_t)e0 * DIM))[i];
  float4 b1 = ((const float4*)(b2 + (size_t)e1 * DIM))[i];
  float4 o;
  o.x = xv.x + w0 * (b2f(a0.x) + b2f(a1.x) + b0.x) + w1 * (b2f(c0.x) + b2f(c1.x) + b1.x);
  o.y = xv.y + w0 * (b2f(a0.y) + b2f(a1.y) + b0.y) + w1 * (b2f(c0.y) + b2f(c1.y) + b1.y);
  o.z = xv.z + w0 * (b2f(a0.z) + b2f(a1.z) + b0.z) + w1 * (b2f(c0.z) + b2f(c1.z) + b1.z);
  o.w = xv.w + w0 * (b2f(a0.w) + b2f(a1.w) + b0.w) + w1 * (b2f(c0.w) + b2f(c1.w) + b1.w);
  ((float4*)(out + (size_t)t * DIM))[i] = o;
}

extern "C" void kernel_launch(void* const* d_in, const int* in_sizes, int n_in,
                              void* d_out, int out_size, void* d_ws, size_t ws_size,
                              hipStream_t stream) {
  const float* x        = (const float*)d_in[0];
  const float* router_w = (const float*)d_in[1];
  const float* router_b = (const float*)d_in[2];
  const float* w1       = (const float*)d_in[3];
  const float* b1       = (const float*)d_in[4];
  const float* w2       = (const float*)d_in[5];
  const float* b2       = (const float*)d_in[6];
  float* out = (float*)d_out;
  char* ws = (char*)d_ws;

  int*   counts  = (int*)(ws + 0);
  int*   cursors = (int*)(ws + 64);
  int*   offsets = (int*)(ws + 128);
  int*   ntilesp = (int*)(ws + 192);
  int*   tlist   = (int*)(ws + 256);
  int*   tidx    = (int*)(ws + 4096);
  float* tw      = (float*)(ws + 36864);
  int*   tslot   = (int*)(ws + 69632);
  // [Xg 17.3][H 69.2][W2c 67.1][W1c 67.1 | EOp(bf16 34.6, aliases W1c after GEMM1)]
  const size_t XG_OFF  = 1u << 20;
  const size_t XG_B    = (size_t)PADROWS * DIM * 2;
  const size_t H_OFF   = XG_OFF + XG_B;
  const size_t H_B     = (size_t)PADROWS * FDIM * 2;
  const size_t W2C_OFF = H_OFF + H_B;
  const size_t WC_B    = (size_t)NEXP * DIM * FDIM * 2;
  const size_t W1C_OFF = W2C_OFF + WC_B;
  const size_t EOP_OFF = W1C_OFF;                          // alias (W1c dead after GEMM1)
  unsigned short* Xg  = (unsigned short*)(ws + XG_OFF);
  unsigned short* H   = (unsigned short*)(ws + H_OFF);
  unsigned short* W2c = (unsigned short*)(ws + W2C_OFF);
  unsigned short* W1c = (unsigned short*)(ws + W1C_OFF);
  unsigned short* EOp = (unsigned short*)(ws + EOP_OFF);   // [2][PADROWS][DIM] bf16

  hipMemsetAsync(ws, 0, 512, stream);
  router_kernel<<<T_TOKENS / 4, 256, 0, stream>>>(x, router_w, router_b, tidx, tw, counts);
  scan_kernel<<<1, 64, 0, stream>>>(counts, offsets, cursors, ntilesp, tlist);
  gather_kernel<<<NASSIGN / 4, 256, 0, stream>>>(x, tidx, cursors, tslot, Xg);
  // weights: streaming fp32 -> bf16, natural K-major layout (no transpose pass)
  convert_bf16<<<4096, 256, 0, stream>>>(w1, W1c, NEXP * DIM * FDIM / 8);
  convert_bf16<<<4096, 256, 0, stream>>>(w2, W2c, NEXP * DIM * FDIM / 8);
  // H = gelu(Xg @ W1 + b1): W1c [E][1024][4096] consumed K-major via tr_read
  ffn_gemm128<true, DIM, FDIM, false, false, DIM, 8><<<dim3(FDIM / 128, 72), 256, 0, stream>>>(
      Xg, W1c, b1, (void*)H, offsets, ntilesp, tlist);
  // EOp[kh] = H @ W2 (K halves, bf16 partials, bias deferred): W2c [E][4096][1024]
  ffn_gemm128<false, FDIM, DIM, true, true, FDIM / 2, 4><<<dim3(DIM / 128 * 2, 72), 256, 0, stream>>>(
      H, W2c, b2, (void*)EOp, offsets, ntilesp, tlist);
  combine_kernel<<<T_TOKENS, 256, 0, stream>>>(x, EOp, tslot, tidx, tw, b2, out);
}

// Round 12
// 500.520 us; speedup vs baseline: 1.0461x; 1.0461x over previous
//
#include <hip/hip_runtime.h>

#define T_TOKENS 4096   // B*S
#define DIM      1024   // D
#define NEXP     8      // E
#define FDIM     4096   // F
#define NASSIGN  8192   // T_TOKENS * K
#define PADROWS  8448
#define M_MAX    6      // max 256-row m-tiles per XCD slot (grid y = 48)

typedef __bf16 bf16x8 __attribute__((ext_vector_type(8)));
typedef float  f32x4  __attribute__((ext_vector_type(4)));
typedef short  short4v __attribute__((ext_vector_type(4)));
typedef short  short8v __attribute__((ext_vector_type(8)));
typedef unsigned short us8 __attribute__((ext_vector_type(8)));

__device__ __forceinline__ unsigned short cvt_bf16(float f) {
  return __builtin_bit_cast(unsigned short, (__bf16)f);   // HW cvt (RNE)
}
__device__ __forceinline__ float b2f(unsigned short h) {
  unsigned u = ((unsigned)h) << 16;
  return __builtin_bit_cast(float, u);
}
__device__ __forceinline__ void gload_lds16(const void* g, void* l) {
  __builtin_amdgcn_global_load_lds(
      (const __attribute__((address_space(1))) void*)g,
      (__attribute__((address_space(3))) void*)l, 16, 0, 0);
}

// paired hardware-transpose LDS reads: lo = k+0..3, hi = k+4..7 (OFF, OFF+1024 bytes)
template <int OFF>
__device__ __forceinline__ void tr2(short4v& lo, short4v& hi, unsigned addr) {
  asm volatile("ds_read_b64_tr_b16 %0, %2 offset:%c3\n\t"
               "ds_read_b64_tr_b16 %1, %2 offset:%c4"
               : "=&v"(lo), "=&v"(hi)
               : "v"(addr), "i"(OFF), "i"(OFF + 1024));
}

// ---------------- fused prep: convert W1 | convert W2 | router (independent ranges) ----
__global__ void prep_kernel(const float* __restrict__ w1, const float* __restrict__ w2,
                            unsigned short* __restrict__ W1c, unsigned short* __restrict__ W2c,
                            const float* __restrict__ x, const float* __restrict__ rw,
                            const float* __restrict__ rb, int* __restrict__ tidx,
                            float* __restrict__ tw, int* __restrict__ counts) {
  int bid = blockIdx.x;
  if (bid < 4096) {   // converts: blocks [0,2048) -> W1, [2048,4096) -> W2
    const float* src = (bid < 2048) ? w1 : w2;
    unsigned short* dst = (bid < 2048) ? W1c : W2c;
    int b = bid & 2047;
    const int n8 = NEXP * DIM * FDIM / 8;
    int stride = 2048 * 256;
    for (int i = b * 256 + threadIdx.x; i < n8; i += stride) {
      float4 v0 = ((const float4*)src)[i * 2];
      float4 v1 = ((const float4*)src)[i * 2 + 1];
      us8 o;
      o[0] = cvt_bf16(v0.x); o[1] = cvt_bf16(v0.y); o[2] = cvt_bf16(v0.z); o[3] = cvt_bf16(v0.w);
      o[4] = cvt_bf16(v1.x); o[5] = cvt_bf16(v1.y); o[6] = cvt_bf16(v1.z); o[7] = cvt_bf16(v1.w);
      ((us8*)dst)[i] = o;
    }
    return;
  }
  // router: blocks [4096, 5120)
  int gid = (bid - 4096) * blockDim.x + threadIdx.x;
  int t = gid >> 6;
  int lane = threadIdx.x & 63;
  if (t >= T_TOKENS) return;
  const float* xr = x + (size_t)t * DIM;
  float acc[NEXP];
#pragma unroll
  for (int e = 0; e < NEXP; ++e) acc[e] = 0.f;
  for (int d = lane; d < DIM; d += 64) {
    float xv = xr[d];
    const float* r = rw + (size_t)d * NEXP;
#pragma unroll
    for (int e = 0; e < NEXP; ++e) acc[e] += xv * r[e];
  }
#pragma unroll
  for (int e = 0; e < NEXP; ++e) {
#pragma unroll
    for (int off = 32; off > 0; off >>= 1) acc[e] += __shfl_xor(acc[e], off);
  }
  if (lane == 0) {
    float lg[NEXP], m = -1e30f;
#pragma unroll
    for (int e = 0; e < NEXP; ++e) { lg[e] = acc[e] + rb[e]; m = fmaxf(m, lg[e]); }
    float p[NEXP], Z = 0.f;
#pragma unroll
    for (int e = 0; e < NEXP; ++e) { p[e] = expf(lg[e] - m); Z += p[e]; }
    int i0 = 0;
#pragma unroll
    for (int e = 1; e < NEXP; ++e) if (p[e] > p[i0]) i0 = e;
    int i1 = (i0 == 0) ? 1 : 0;
#pragma unroll
    for (int e = 0; e < NEXP; ++e) if (e != i0 && p[e] > p[i1]) i1 = e;
    float q0 = p[i0] / Z, q1 = p[i1] / Z;
    float s = q0 + q1 + 1e-8f;
    tidx[t * 2] = i0; tidx[t * 2 + 1] = i1;
    tw[t * 2] = q0 / s; tw[t * 2 + 1] = q1 / s;
    atomicAdd(&counts[i0], 1); atomicAdd(&counts[i1], 1);
  }
}

// ---------------- scan: offsets, cursors, 256-row tile list ----------------
__global__ void scan_kernel(const int* __restrict__ counts, int* __restrict__ offsets,
                            int* __restrict__ cursors, int* __restrict__ ntiles_p,
                            int* __restrict__ tlist) {
  __shared__ int mts[NEXP], tstart[NEXP];
  int l = threadIdx.x;
  if (l == 0) {
    int s = 0, t = 0;
    for (int e = 0; e < NEXP; ++e) {
      offsets[e] = s; cursors[e] = s;
      int m = (counts[e] + 255) >> 8;
      mts[e] = m; tstart[e] = t;
      s += counts[e]; t += m;
    }
    offsets[NEXP] = s;
    *ntiles_p = t;   // ~34 typical, <= 48
  }
  __syncthreads();
  if (l < NEXP) {
    int t0 = tstart[l], m = mts[l];
    for (int mt = 0; mt < m; ++mt) tlist[t0 + mt] = (l << 8) | mt;
  }
}

// ---------------- gather x rows (fp32 -> bf16) ----------------
__global__ void gather_kernel(const float* __restrict__ x, const int* __restrict__ tidx,
                              int* __restrict__ cursors, int* __restrict__ tslot,
                              unsigned short* __restrict__ Xg) {
  int aid = (blockIdx.x * blockDim.x + threadIdx.x) >> 6;
  int lane = threadIdx.x & 63;
  if (aid >= NASSIGN) return;
  int t = aid >> 1, k = aid & 1;
  int e = tidx[t * 2 + k];
  int slot = 0;
  if (lane == 0) {
    slot = atomicAdd(&cursors[e], 1);
    tslot[t * 2 + k] = slot;
  }
  slot = __shfl(slot, 0);
  const float4* xr = (const float4*)(x + (size_t)t * DIM);
  ushort4* dst = (ushort4*)(Xg + (size_t)slot * DIM);
#pragma unroll
  for (int i = 0; i < 4; ++i) {
    int idx = i * 64 + lane;
    float4 v = xr[idx];
    ushort4 o;
    o.x = cvt_bf16(v.x); o.y = cvt_bf16(v.y); o.z = cvt_bf16(v.z); o.w = cvt_bf16(v.w);
    dst[idx] = o;
  }
}

// ---------------- 256x128 grouped GEMM, 8 waves (4M x 2N), single-buffer 2-phase -------
// A: [slots][KTOT] bf16 (K-major, ds_read_b128 + XOR swizzle). Bc: [E][KTOT][NN] bf16
// (natural K-major weights), consumed via ds_read_b64_tr_b16 subtiled LDS (R11-verified).
// __launch_bounds__(512,4): 128 regs/wave (64 VGPR + 64 AGPR acc), 2 blocks/CU, LDS 48KB.
// XCD mapping: balanced contiguous runs -- XCD x owns q+(x<r) consecutive tlist entries.
#define COMPUTE_KK(KK)                                                                   \
  {                                                                                      \
    short4v lo[4], hi[4];                                                                \
    tr2<(KK) * 8192 + 0>(lo[0], hi[0], vb2);                                             \
    tr2<(KK) * 8192 + 128>(lo[1], hi[1], vb2);                                           \
    tr2<(KK) * 8192 + 256>(lo[2], hi[2], vb2);                                           \
    tr2<(KK) * 8192 + 384>(lo[3], hi[3], vb2);                                           \
    int cb = ((KK) * 64 + (l >> 4) * 16) ^ ((l & 7) << 4);                               \
    bf16x8 af[4];                                                                        \
    _Pragma("unroll") for (int i = 0; i < 4; ++i) {                                      \
      int row = wm * 64 + i * 16 + (l & 15);                                             \
      af[i] = *(const bf16x8*)((const char*)&As[0] + row * 128 + cb);                    \
    }                                                                                    \
    asm volatile("s_waitcnt lgkmcnt(0)" ::: "memory");                                   \
    __builtin_amdgcn_sched_barrier(0);                                                   \
    _Pragma("unroll") for (int j = 0; j < 4; ++j) {                                      \
      bf16x8 bfr = __builtin_bit_cast(                                                   \
          bf16x8, (short8v)__builtin_shufflevector(lo[j], hi[j], 0, 1, 2, 3, 4, 5, 6, 7)); \
      _Pragma("unroll") for (int i = 0; i < 4; ++i)                                      \
        acc[i][j] = __builtin_amdgcn_mfma_f32_16x16x32_bf16(af[i], bfr, acc[i][j], 0, 0, 0); \
    }                                                                                    \
  }

template <bool GELU, int KTOT, int NN, bool PARTIAL, int NSPLIT, int NCH>
__global__ __launch_bounds__(512, 4) void ffn_gemm256x128(
    const unsigned short* __restrict__ A, const unsigned short* __restrict__ Bc,
    const float* __restrict__ bias, void* __restrict__ OutP,
    const int* __restrict__ offsets, const int* __restrict__ ntiles_p,
    const int* __restrict__ tlist) {
  int gx = gridDim.x;
  int orig = blockIdx.y * gx + blockIdx.x;
  int xcd   = orig & 7;
  int local = orig >> 3;               // [0, gx*M_MAX)
  int nc  = local / (NCH * M_MAX);
  int rem = local - nc * (NCH * M_MAX);
  int m   = rem / NCH;
  int nn  = rem - m * NCH;
  int xb  = nc * NCH + nn;

  int ntiles = *ntiles_p;
  int q = ntiles >> 3, r = ntiles & 7;
  int cnt   = q + (xcd < r ? 1 : 0);
  if (m >= cnt) return;
  int yb = xcd * q + (xcd < r ? xcd : r) + m;   // contiguous balanced run

  int kh = 0;
  if (NSPLIT > 1) { kh = xb % NSPLIT; xb /= NSPLIT; }

  int ent = tlist[yb];
  int e = ent >> 8, mt = ent & 255;
  int off = offsets[e];
  int n_e = offsets[e + 1] - off;
  int row0 = off + mt * 256;
  if (mt * 256 >= n_e) return;
  int rows_valid = n_e - mt * 256; if (rows_valid > 256) rows_valid = 256;
  int n0 = xb * 128;
  // split-K spans in 64-steps: first (ksteps % NSPLIT) splits get one extra step
  constexpr int KSTEPS = KTOT / 64;
  int ks0 = KSTEPS / NSPLIT, krem = KSTEPS % NSPLIT;
  int ksteps = ks0 + (kh < krem ? 1 : 0);
  int kbase  = (kh * ks0 + (kh < krem ? kh : krem)) * 64;

  __shared__ unsigned short As[256 * 64];   // 32 KB
  __shared__ unsigned short Bs[64 * 128];   // 16 KB

  int tid = threadIdx.x, w = tid >> 6, l = tid & 63;
  int wm = w >> 1, wn = w & 1;   // 4M x 2N

  f32x4 acc[4][4] = {};

  const unsigned short* Ab = A + (size_t)row0 * KTOT;
  const unsigned short* Bg = Bc + (size_t)e * KTOT * NN + n0;
  int srow = l >> 3;                     // A: row within 8-row group
  int scol = ((l & 7) ^ (l >> 3)) * 8;   // A: pre-swizzled source chunk (shorts)
  int kr   = (l >> 1) & 3;               // B: k row within 4-row subtile
  int ncol = ((l >> 3) << 4) + ((l & 1) << 3);   // B: n col (16B chunk)

  unsigned bsOff = (unsigned)(uintptr_t)(__attribute__((address_space(3))) unsigned short*)Bs;
  unsigned vb2 = bsOff + ((unsigned)(l >> 4) << 11) + ((unsigned)(l & 15) << 3)
               + ((unsigned)wn << 9);

#pragma unroll 1
  for (int ks = 0; ks < ksteps; ++ks) {
    int k0 = kbase + ks * 64;
    // A: 8 waves x 4 iters x 8 rows = 256; B: 8 waves x 2 iters (kg groups)
#pragma unroll
    for (int i = 0; i < 4; ++i) {
      int R = w * 32 + i * 8;
      gload_lds16(Ab + (size_t)(R + srow) * KTOT + k0 + scol, &As[R * 64]);
    }
#pragma unroll
    for (int i = 0; i < 2; ++i) {
      int kg = w * 2 + i;
      gload_lds16(Bg + (size_t)(k0 + kg * 4 + kr) * NN + ncol, &Bs[kg * 512]);
    }
    __syncthreads();   // vmcnt(0) drain; resident blocks overlap each other
    COMPUTE_KK(0)
    COMPUTE_KK(1)
    __syncthreads();
  }

  int cr = (l >> 4) * 4, cc = l & 15;
#pragma unroll
  for (int i = 0; i < 4; ++i) {
#pragma unroll
    for (int rr = 0; rr < 4; ++rr) {
      int rl = wm * 64 + i * 16 + cr + rr;
      if (rl < rows_valid) {
#pragma unroll
        for (int j = 0; j < 4; ++j) {
          int col = n0 + wn * 64 + j * 16 + cc;
          unsigned short* Oh = (unsigned short*)OutP;
          if (PARTIAL) {
            Oh[((size_t)(kh * PADROWS) + row0 + rl) * NN + col] = cvt_bf16(acc[i][j][rr]);
          } else {
            float v = acc[i][j][rr] + bias[(size_t)e * NN + col];
            if (GELU) v = 0.5f * v * (1.0f + erff(v * 0.70710678118654752f));
            Oh[(size_t)(row0 + rl) * NN + col] = cvt_bf16(v);
          }
        }
      }
    }
  }
}

// ---------------- combine: out = x + sum_k w_k*(sum_kh EOp[kh][s_k] + b2[e_k]) ----------
__global__ void combine_kernel(const float* __restrict__ x, const unsigned short* __restrict__ EOp,
                               const int* __restrict__ tslot, const int* __restrict__ tidx,
                               const float* __restrict__ tw, const float* __restrict__ b2,
                               float* __restrict__ out) {
  int t = blockIdx.x;
  int s0 = tslot[t * 2], s1 = tslot[t * 2 + 1];
  int e0 = tidx[t * 2], e1 = tidx[t * 2 + 1];
  float w0 = tw[t * 2], w1 = tw[t * 2 + 1];
  int i = threadIdx.x;
  float4 xv = ((const float4*)(x + (size_t)t * DIM))[i];
  float4 b0 = ((const float4*)(b2 + (size_t)e0 * DIM))[i];
  float4 b1 = ((const float4*)(b2 + (size_t)e1 * DIM))[i];
  float sa[4] = {b0.x, b0.y, b0.z, b0.w};
  float sb[4] = {b1.x, b1.y, b1.z, b1.w};
#pragma unroll
  for (int kh = 0; kh < 3; ++kh) {
    ushort4 a = ((const ushort4*)(EOp + ((size_t)kh * PADROWS + s0) * DIM))[i];
    ushort4 c = ((const ushort4*)(EOp + ((size_t)kh * PADROWS + s1) * DIM))[i];
    sa[0] += b2f(a.x); sa[1] += b2f(a.y); sa[2] += b2f(a.z); sa[3] += b2f(a.w);
    sb[0] += b2f(c.x); sb[1] += b2f(c.y); sb[2] += b2f(c.z); sb[3] += b2f(c.w);
  }
  float4 o;
  o.x = xv.x + w0 * sa[0] + w1 * sb[0];
  o.y = xv.y + w0 * sa[1] + w1 * sb[1];
  o.z = xv.z + w0 * sa[2] + w1 * sb[2];
  o.w = xv.w + w0 * sa[3] + w1 * sb[3];
  ((float4*)(out + (size_t)t * DIM))[i] = o;
}

extern "C" void kernel_launch(void* const* d_in, const int* in_sizes, int n_in,
                              void* d_out, int out_size, void* d_ws, size_t ws_size,
                              hipStream_t stream) {
  const float* x        = (const float*)d_in[0];
  const float* router_w = (const float*)d_in[1];
  const float* router_b = (const float*)d_in[2];
  const float* w1       = (const float*)d_in[3];
  const float* b1       = (const float*)d_in[4];
  const float* w2       = (const float*)d_in[5];
  const float* b2       = (const float*)d_in[6];
  float* out = (float*)d_out;
  char* ws = (char*)d_ws;

  int*   counts  = (int*)(ws + 0);
  int*   cursors = (int*)(ws + 64);
  int*   offsets = (int*)(ws + 128);
  int*   ntilesp = (int*)(ws + 192);
  int*   tlist   = (int*)(ws + 256);
  int*   tidx    = (int*)(ws + 4096);
  float* tw      = (float*)(ws + 36864);
  int*   tslot   = (int*)(ws + 69632);
  // [Xg 17.3][H 69.2][W2c 67.1][W1c 67.1 | EOp(bf16 x3, 51.9, aliases W1c after GEMM1)]
  const size_t XG_OFF  = 1u << 20;
  const size_t XG_B    = (size_t)PADROWS * DIM * 2;
  const size_t H_OFF   = XG_OFF + XG_B;
  const size_t H_B     = (size_t)PADROWS * FDIM * 2;
  const size_t W2C_OFF = H_OFF + H_B;
  const size_t WC_B    = (size_t)NEXP * DIM * FDIM * 2;
  const size_t W1C_OFF = W2C_OFF + WC_B;
  const size_t EOP_OFF = W1C_OFF;                          // alias (W1c dead after GEMM1)
  unsigned short* Xg  = (unsigned short*)(ws + XG_OFF);
  unsigned short* H   = (unsigned short*)(ws + H_OFF);
  unsigned short* W2c = (unsigned short*)(ws + W2C_OFF);
  unsigned short* W1c = (unsigned short*)(ws + W1C_OFF);
  unsigned short* EOp = (unsigned short*)(ws + EOP_OFF);   // [3][PADROWS][DIM] bf16

  hipMemsetAsync(ws, 0, 512, stream);
  // fused: convert W1 | convert W2 | router
  prep_kernel<<<5120, 256, 0, stream>>>(w1, w2, W1c, W2c, x, router_w, router_b,
                                        tidx, tw, counts);
  scan_kernel<<<1, 64, 0, stream>>>(counts, offsets, cursors, ntilesp, tlist);
  gather_kernel<<<NASSIGN / 4, 256, 0, stream>>>(x, tidx, cursors, tslot, Xg);
  // H = gelu(Xg @ W1 + b1): 256x128 tiles, x = 32 n-tiles, y = 48 (8 XCD x M_MAX)
  ffn_gemm256x128<true, DIM, FDIM, false, 1, 8><<<dim3(FDIM / 128, 48), 512, 0, stream>>>(
      Xg, W1c, b1, (void*)H, offsets, ntilesp, tlist);
  // EOp[kh] = H @ W2 (split-K x3 bf16 partials, bias deferred): x = 8 n-tiles x 3 kh
  ffn_gemm256x128<false, FDIM, DIM, true, 3, 24><<<dim3(DIM / 128 * 3, 48), 512, 0, stream>>>(
      H, W2c, b2, (void*)EOp, offsets, ntilesp, tlist);
  combine_kernel<<<T_TOKENS, 256, 0, stream>>>(x, EOp, tslot, tidx, tw, b2, out);
}

// Round 13
// 363.678 us; speedup vs baseline: 1.4397x; 1.3763x over previous
//
#include <hip/hip_runtime.h>

#define T_TOKENS 4096   // B*S
#define DIM      1024   // D
#define NEXP     8      // E
#define FDIM     4096   // F
#define NASSIGN  8192   // T_TOKENS * K
#define PADROWS  8448
#define M_MAX    6      // max 256-row m-tiles per XCD slot (grid y = 48)

typedef __bf16 bf16x8 __attribute__((ext_vector_type(8)));
typedef float  f32x4  __attribute__((ext_vector_type(4)));
typedef short  short4v __attribute__((ext_vector_type(4)));
typedef short  short8v __attribute__((ext_vector_type(8)));

__device__ __forceinline__ unsigned short cvt_bf16(float f) {
  return __builtin_bit_cast(unsigned short, (__bf16)f);   // HW cvt (RNE)
}
__device__ __forceinline__ float b2f(unsigned short h) {
  unsigned u = ((unsigned)h) << 16;
  return __builtin_bit_cast(float, u);
}
__device__ __forceinline__ void gload_lds16(const void* g, void* l) {
  __builtin_amdgcn_global_load_lds(
      (const __attribute__((address_space(1))) void*)g,
      (__attribute__((address_space(3))) void*)l, 16, 0, 0);
}

// paired hardware-transpose LDS reads: lo = k+0..3, hi = k+4..7 (OFF, OFF+1024 bytes)
template <int OFF>
__device__ __forceinline__ void tr2(short4v& lo, short4v& hi, unsigned addr) {
  asm volatile("ds_read_b64_tr_b16 %0, %2 offset:%c3\n\t"
               "ds_read_b64_tr_b16 %1, %2 offset:%c4"
               : "=&v"(lo), "=&v"(hi)
               : "v"(addr), "i"(OFF), "i"(OFF + 1024));
}

// ---------------- fused prep: convert W1 | convert W2 | router (NO atomics) ----------
__global__ void prep_kernel(const float* __restrict__ w1, const float* __restrict__ w2,
                            unsigned short* __restrict__ W1c, unsigned short* __restrict__ W2c,
                            const float* __restrict__ x, const float* __restrict__ rw,
                            const float* __restrict__ rb, int* __restrict__ tidx,
                            float* __restrict__ tw) {
  int bid = blockIdx.x;
  if (bid < 4096) {   // converts: [0,2048) -> W1, [2048,4096) -> W2
    const float* src = (bid < 2048) ? w1 : w2;
    unsigned short* dst = (bid < 2048) ? W1c : W2c;
    int b = bid & 2047;
    const int stride = 2048 * 256;   // 16 iters cover 8*1024*4096/4 float4s exactly
#pragma unroll
    for (int j = 0; j < 16; ++j) {
      int i = b * 256 + (int)threadIdx.x + j * stride;
      float4 v = ((const float4*)src)[i];
      ushort4 o;
      o.x = cvt_bf16(v.x); o.y = cvt_bf16(v.y); o.z = cvt_bf16(v.z); o.w = cvt_bf16(v.w);
      ((ushort4*)dst)[i] = o;   // per-instruction coalesced both sides
    }
    return;
  }
  // router: blocks [4096, 5120), one wave per token
  int gid = (bid - 4096) * blockDim.x + threadIdx.x;
  int t = gid >> 6;
  int lane = threadIdx.x & 63;
  if (t >= T_TOKENS) return;
  const float* xr = x + (size_t)t * DIM;
  float acc[NEXP];
#pragma unroll
  for (int e = 0; e < NEXP; ++e) acc[e] = 0.f;
  for (int d = lane; d < DIM; d += 64) {
    float xv = xr[d];
    const float* r = rw + (size_t)d * NEXP;
#pragma unroll
    for (int e = 0; e < NEXP; ++e) acc[e] += xv * r[e];
  }
#pragma unroll
  for (int e = 0; e < NEXP; ++e) {
#pragma unroll
    for (int off = 32; off > 0; off >>= 1) acc[e] += __shfl_xor(acc[e], off);
  }
  if (lane == 0) {
    float lg[NEXP], m = -1e30f;
#pragma unroll
    for (int e = 0; e < NEXP; ++e) { lg[e] = acc[e] + rb[e]; m = fmaxf(m, lg[e]); }
    float p[NEXP], Z = 0.f;
#pragma unroll
    for (int e = 0; e < NEXP; ++e) { p[e] = expf(lg[e] - m); Z += p[e]; }
    int i0 = 0;
#pragma unroll
    for (int e = 1; e < NEXP; ++e) if (p[e] > p[i0]) i0 = e;
    int i1 = (i0 == 0) ? 1 : 0;
#pragma unroll
    for (int e = 0; e < NEXP; ++e) if (e != i0 && p[e] > p[i1]) i1 = e;
    float q0 = p[i0] / Z, q1 = p[i1] / Z;
    float s = q0 + q1 + 1e-8f;
    tidx[t * 2] = i0; tidx[t * 2 + 1] = i1;
    tw[t * 2] = q0 / s; tw[t * 2 + 1] = q1 / s;
  }
}

// ---------------- scan: histogram + prefix + deterministic slot assignment -------------
// 1 block, 256 threads; each owns 32 assignments. Replaces ALL contended atomics.
__global__ __launch_bounds__(256) void scan_kernel(
    const int* __restrict__ tidx, int* __restrict__ offsets, int* __restrict__ ntiles_p,
    int* __restrict__ tlist, int* __restrict__ tslot) {
  __shared__ int lh[256][NEXP];   // per-chunk per-expert: count -> exclusive prefix
  __shared__ int offs[NEXP + 1];
  int t = threadIdx.x;
  int base = t * 32;
  int h[NEXP];
#pragma unroll
  for (int e = 0; e < NEXP; ++e) h[e] = 0;
#pragma unroll 1
  for (int a = 0; a < 32; ++a) {
    int e = tidx[base + a];
#pragma unroll
    for (int q = 0; q < NEXP; ++q) h[q] += (e == q);   // compile-time index: registers
  }
#pragma unroll
  for (int e = 0; e < NEXP; ++e) lh[t][e] = h[e];
  __syncthreads();
  if (t < NEXP) {   // per-expert exclusive scan over the 256 chunks
    int run = 0;
    for (int c = 0; c < 256; ++c) { int v = lh[c][t]; lh[c][t] = run; run += v; }
    offs[t + 1] = run;   // count[e] (temporarily)
  }
  __syncthreads();
  if (t == 0) {
    int s = 0, nt = 0;
    for (int e = 0; e < NEXP; ++e) {
      int cnt = offs[e + 1];   // read count BEFORE overwriting (sequential-safe)
      offs[e] = s;             // exclusive expert start for phase 3
      offsets[e] = s;
      int m = (cnt + 255) >> 8;
      for (int mt = 0; mt < m; ++mt) tlist[nt++] = (e << 8) | mt;
      s += cnt;
    }
    offsets[NEXP] = s;
    *ntiles_p = nt;   // <= 48
  }
  __syncthreads();
#pragma unroll 1
  for (int a = 0; a < 32; ++a) {   // deterministic slots in aid order
    int e = tidx[base + a];
    tslot[base + a] = offs[e] + lh[t][e];
    lh[t][e] += 1;
  }
}

// ---------------- gather x rows (fp32 -> bf16), atomic-free ----------------
__global__ void gather_kernel(const float* __restrict__ x, const int* __restrict__ tslot,
                              unsigned short* __restrict__ Xg) {
  int aid = (blockIdx.x * blockDim.x + threadIdx.x) >> 6;
  int lane = threadIdx.x & 63;
  if (aid >= NASSIGN) return;
  int t = aid >> 1;
  int slot = tslot[aid];
  const float4* xr = (const float4*)(x + (size_t)t * DIM);
  ushort4* dst = (ushort4*)(Xg + (size_t)slot * DIM);
#pragma unroll
  for (int i = 0; i < 4; ++i) {
    int idx = i * 64 + lane;
    float4 v = xr[idx];
    ushort4 o;
    o.x = cvt_bf16(v.x); o.y = cvt_bf16(v.y); o.z = cvt_bf16(v.z); o.w = cvt_bf16(v.w);
    dst[idx] = o;
  }
}

// ---------------- 256x128 grouped GEMM, 8 waves (4M x 2N), single-buffer 2-phase -------
// (unchanged from R12 -- frozen for attribution)
#define COMPUTE_KK(KK)                                                                   \
  {                                                                                      \
    short4v lo[4], hi[4];                                                                \
    tr2<(KK) * 8192 + 0>(lo[0], hi[0], vb2);                                             \
    tr2<(KK) * 8192 + 128>(lo[1], hi[1], vb2);                                           \
    tr2<(KK) * 8192 + 256>(lo[2], hi[2], vb2);                                           \
    tr2<(KK) * 8192 + 384>(lo[3], hi[3], vb2);                                           \
    int cb = ((KK) * 64 + (l >> 4) * 16) ^ ((l & 7) << 4);                               \
    bf16x8 af[4];                                                                        \
    _Pragma("unroll") for (int i = 0; i < 4; ++i) {                                      \
      int row = wm * 64 + i * 16 + (l & 15);                                             \
      af[i] = *(const bf16x8*)((const char*)&As[0] + row * 128 + cb);                    \
    }                                                                                    \
    asm volatile("s_waitcnt lgkmcnt(0)" ::: "memory");                                   \
    __builtin_amdgcn_sched_barrier(0);                                                   \
    _Pragma("unroll") for (int j = 0; j < 4; ++j) {                                      \
      bf16x8 bfr = __builtin_bit_cast(                                                   \
          bf16x8, (short8v)__builtin_shufflevector(lo[j], hi[j], 0, 1, 2, 3, 4, 5, 6, 7)); \
      _Pragma("unroll") for (int i = 0; i < 4; ++i)                                      \
        acc[i][j] = __builtin_amdgcn_mfma_f32_16x16x32_bf16(af[i], bfr, acc[i][j], 0, 0, 0); \
    }                                                                                    \
  }

template <bool GELU, int KTOT, int NN, bool PARTIAL, int NSPLIT, int NCH>
__global__ __launch_bounds__(512, 4) void ffn_gemm256x128(
    const unsigned short* __restrict__ A, const unsigned short* __restrict__ Bc,
    const float* __restrict__ bias, void* __restrict__ OutP,
    const int* __restrict__ offsets, const int* __restrict__ ntiles_p,
    const int* __restrict__ tlist) {
  int gx = gridDim.x;
  int orig = blockIdx.y * gx + blockIdx.x;
  int xcd   = orig & 7;
  int local = orig >> 3;               // [0, gx*M_MAX)
  int nc  = local / (NCH * M_MAX);
  int rem = local - nc * (NCH * M_MAX);
  int m   = rem / NCH;
  int nn  = rem - m * NCH;
  int xb  = nc * NCH + nn;

  int ntiles = *ntiles_p;
  int q = ntiles >> 3, r = ntiles & 7;
  int cnt   = q + (xcd < r ? 1 : 0);
  if (m >= cnt) return;
  int yb = xcd * q + (xcd < r ? xcd : r) + m;   // contiguous balanced run

  int kh = 0;
  if (NSPLIT > 1) { kh = xb % NSPLIT; xb /= NSPLIT; }

  int ent = tlist[yb];
  int e = ent >> 8, mt = ent & 255;
  int off = offsets[e];
  int n_e = offsets[e + 1] - off;
  int row0 = off + mt * 256;
  if (mt * 256 >= n_e) return;
  int rows_valid = n_e - mt * 256; if (rows_valid > 256) rows_valid = 256;
  int n0 = xb * 128;
  constexpr int KSTEPS = KTOT / 64;
  int ks0 = KSTEPS / NSPLIT, krem = KSTEPS % NSPLIT;
  int ksteps = ks0 + (kh < krem ? 1 : 0);
  int kbase  = (kh * ks0 + (kh < krem ? kh : krem)) * 64;

  __shared__ unsigned short As[256 * 64];   // 32 KB
  __shared__ unsigned short Bs[64 * 128];   // 16 KB

  int tid = threadIdx.x, w = tid >> 6, l = tid & 63;
  int wm = w >> 1, wn = w & 1;   // 4M x 2N

  f32x4 acc[4][4] = {};

  const unsigned short* Ab = A + (size_t)row0 * KTOT;
  const unsigned short* Bg = Bc + (size_t)e * KTOT * NN + n0;
  int srow = l >> 3;
  int scol = ((l & 7) ^ (l >> 3)) * 8;
  int kr   = (l >> 1) & 3;
  int ncol = ((l >> 3) << 4) + ((l & 1) << 3);

  unsigned bsOff = (unsigned)(uintptr_t)(__attribute__((address_space(3))) unsigned short*)Bs;
  unsigned vb2 = bsOff + ((unsigned)(l >> 4) << 11) + ((unsigned)(l & 15) << 3)
               + ((unsigned)wn << 9);

#pragma unroll 1
  for (int ks = 0; ks < ksteps; ++ks) {
    int k0 = kbase + ks * 64;
#pragma unroll
    for (int i = 0; i < 4; ++i) {
      int R = w * 32 + i * 8;
      gload_lds16(Ab + (size_t)(R + srow) * KTOT + k0 + scol, &As[R * 64]);
    }
#pragma unroll
    for (int i = 0; i < 2; ++i) {
      int kg = w * 2 + i;
      gload_lds16(Bg + (size_t)(k0 + kg * 4 + kr) * NN + ncol, &Bs[kg * 512]);
    }
    __syncthreads();
    COMPUTE_KK(0)
    COMPUTE_KK(1)
    __syncthreads();
  }

  int cr = (l >> 4) * 4, cc = l & 15;
#pragma unroll
  for (int i = 0; i < 4; ++i) {
#pragma unroll
    for (int rr = 0; rr < 4; ++rr) {
      int rl = wm * 64 + i * 16 + cr + rr;
      if (rl < rows_valid) {
#pragma unroll
        for (int j = 0; j < 4; ++j) {
          int col = n0 + wn * 64 + j * 16 + cc;
          unsigned short* Oh = (unsigned short*)OutP;
          if (PARTIAL) {
            Oh[((size_t)(kh * PADROWS) + row0 + rl) * NN + col] = cvt_bf16(acc[i][j][rr]);
          } else {
            float v = acc[i][j][rr] + bias[(size_t)e * NN + col];
            if (GELU) v = 0.5f * v * (1.0f + erff(v * 0.70710678118654752f));
            Oh[(size_t)(row0 + rl) * NN + col] = cvt_bf16(v);
          }
        }
      }
    }
  }
}

// ---------------- combine: out = x + sum_k w_k*(sum_kh EOp[kh][s_k] + b2[e_k]) ----------
__global__ void combine_kernel(const float* __restrict__ x, const unsigned short* __restrict__ EOp,
                               const int* __restrict__ tslot, const int* __restrict__ tidx,
                               const float* __restrict__ tw, const float* __restrict__ b2,
                               float* __restrict__ out) {
  int t = blockIdx.x;
  int s0 = tslot[t * 2], s1 = tslot[t * 2 + 1];
  int e0 = tidx[t * 2], e1 = tidx[t * 2 + 1];
  float w0 = tw[t * 2], w1 = tw[t * 2 + 1];
  int i = threadIdx.x;
  float4 xv = ((const float4*)(x + (size_t)t * DIM))[i];
  float4 b0 = ((const float4*)(b2 + (size_t)e0 * DIM))[i];
  float4 b1 = ((const float4*)(b2 + (size_t)e1 * DIM))[i];
  float sa[4] = {b0.x, b0.y, b0.z, b0.w};
  float sb[4] = {b1.x, b1.y, b1.z, b1.w};
#pragma unroll
  for (int kh = 0; kh < 3; ++kh) {
    ushort4 a = ((const ushort4*)(EOp + ((size_t)kh * PADROWS + s0) * DIM))[i];
    ushort4 c = ((const ushort4*)(EOp + ((size_t)kh * PADROWS + s1) * DIM))[i];
    sa[0] += b2f(a.x); sa[1] += b2f(a.y); sa[2] += b2f(a.z); sa[3] += b2f(a.w);
    sb[0] += b2f(c.x); sb[1] += b2f(c.y); sb[2] += b2f(c.z); sb[3] += b2f(c.w);
  }
  float4 o;
  o.x = xv.x + w0 * sa[0] + w1 * sb[0];
  o.y = xv.y + w0 * sa[1] + w1 * sb[1];
  o.z = xv.z + w0 * sa[2] + w1 * sb[2];
  o.w = xv.w + w0 * sa[3] + w1 * sb[3];
  ((float4*)(out + (size_t)t * DIM))[i] = o;
}

extern "C" void kernel_launch(void* const* d_in, const int* in_sizes, int n_in,
                              void* d_out, int out_size, void* d_ws, size_t ws_size,
                              hipStream_t stream) {
  const float* x        = (const float*)d_in[0];
  const float* router_w = (const float*)d_in[1];
  const float* router_b = (const float*)d_in[2];
  const float* w1       = (const float*)d_in[3];
  const float* b1       = (const float*)d_in[4];
  const float* w2       = (const float*)d_in[5];
  const float* b2       = (const float*)d_in[6];
  float* out = (float*)d_out;
  char* ws = (char*)d_ws;

  int*   offsets = (int*)(ws + 128);
  int*   ntilesp = (int*)(ws + 192);
  int*   tlist   = (int*)(ws + 256);
  int*   tidx    = (int*)(ws + 4096);
  float* tw      = (float*)(ws + 36864);
  int*   tslot   = (int*)(ws + 69632);
  // [Xg 17.3][H 69.2][W2c 67.1][W1c 67.1 | EOp(bf16 x3, 51.9, aliases W1c after GEMM1)]
  const size_t XG_OFF  = 1u << 20;
  const size_t XG_B    = (size_t)PADROWS * DIM * 2;
  const size_t H_OFF   = XG_OFF + XG_B;
  const size_t H_B     = (size_t)PADROWS * FDIM * 2;
  const size_t W2C_OFF = H_OFF + H_B;
  const size_t WC_B    = (size_t)NEXP * DIM * FDIM * 2;
  const size_t W1C_OFF = W2C_OFF + WC_B;
  const size_t EOP_OFF = W1C_OFF;                          // alias (W1c dead after GEMM1)
  unsigned short* Xg  = (unsigned short*)(ws + XG_OFF);
  unsigned short* H   = (unsigned short*)(ws + H_OFF);
  unsigned short* W2c = (unsigned short*)(ws + W2C_OFF);
  unsigned short* W1c = (unsigned short*)(ws + W1C_OFF);
  unsigned short* EOp = (unsigned short*)(ws + EOP_OFF);   // [3][PADROWS][DIM] bf16

  // fused: convert W1 | convert W2 | router (atomic-free)
  prep_kernel<<<5120, 256, 0, stream>>>(w1, w2, W1c, W2c, x, router_w, router_b, tidx, tw);
  scan_kernel<<<1, 256, 0, stream>>>(tidx, offsets, ntilesp, tlist, tslot);
  gather_kernel<<<NASSIGN / 4, 256, 0, stream>>>(x, tslot, Xg);
  // H = gelu(Xg @ W1 + b1): 256x128 tiles, x = 32 n-tiles, y = 48 (8 XCD x M_MAX)
  ffn_gemm256x128<true, DIM, FDIM, false, 1, 8><<<dim3(FDIM / 128, 48), 512, 0, stream>>>(
      Xg, W1c, b1, (void*)H, offsets, ntilesp, tlist);
  // EOp[kh] = H @ W2 (split-K x3 bf16 partials, bias deferred): x = 8 n-tiles x 3 kh
  ffn_gemm256x128<false, FDIM, DIM, true, 3, 24><<<dim3(DIM / 128 * 3, 48), 512, 0, stream>>>(
      H, W2c, b2, (void*)EOp, offsets, ntilesp, tlist);
  combine_kernel<<<T_TOKENS, 256, 0, stream>>>(x, EOp, tslot, tidx, tw, b2, out);
}

// Round 14
// 350.044 us; speedup vs baseline: 1.4958x; 1.0390x over previous
//
#include <hip/hip_runtime.h>

#define T_TOKENS 4096   // B*S
#define DIM      1024   // D
#define NEXP     8      // E
#define FDIM     4096   // F
#define NASSIGN  8192   // T_TOKENS * K
#define PADROWS  8448

typedef __bf16 bf16x8 __attribute__((ext_vector_type(8)));
typedef float  f32x4  __attribute__((ext_vector_type(4)));
typedef short  short4v __attribute__((ext_vector_type(4)));
typedef short  short8v __attribute__((ext_vector_type(8)));

__device__ __forceinline__ unsigned short cvt_bf16(float f) {
  return __builtin_bit_cast(unsigned short, (__bf16)f);   // HW cvt (RNE)
}
__device__ __forceinline__ float b2f(unsigned short h) {
  unsigned u = ((unsigned)h) << 16;
  return __builtin_bit_cast(float, u);
}
__device__ __forceinline__ void gload_lds16(const void* g, void* l) {
  __builtin_amdgcn_global_load_lds(
      (const __attribute__((address_space(1))) void*)g,
      (__attribute__((address_space(3))) void*)l, 16, 0, 0);
}

// paired hardware-transpose LDS reads: lo = k+0..3, hi = k+4..7 (OFF, OFF+1024 bytes)
template <int OFF>
__device__ __forceinline__ void tr2(short4v& lo, short4v& hi, unsigned addr) {
  asm volatile("ds_read_b64_tr_b16 %0, %2 offset:%c3\n\t"
               "ds_read_b64_tr_b16 %1, %2 offset:%c4"
               : "=&v"(lo), "=&v"(hi)
               : "v"(addr), "i"(OFF), "i"(OFF + 1024));
}

// ---------------- fused prep: convert W1 | convert W2 | router (atomic-free) ----------
// Converts are BLOCK-CONTIGUOUS: block owns a 64KB span, wave steps 1KB/iter
// (page-friendly; R13's 8MB-stride grid-stride showed all-pipes-idle at 150us).
__global__ void prep_kernel(const float* __restrict__ w1, const float* __restrict__ w2,
                            unsigned short* __restrict__ W1c, unsigned short* __restrict__ W2c,
                            const float* __restrict__ x, const float* __restrict__ rw,
                            const float* __restrict__ rb, int* __restrict__ tidx,
                            float* __restrict__ tw) {
  int bid = blockIdx.x;
  if (bid < 4096) {   // converts: [0,2048) -> W1, [2048,4096) -> W2
    const float* src = (bid < 2048) ? w1 : w2;
    unsigned short* dst = (bid < 2048) ? W1c : W2c;
    int base = (bid & 2047) * 4096;   // float4 units; block covers 64KB contiguous
#pragma unroll
    for (int j = 0; j < 16; ++j) {
      int i = base + j * 256 + (int)threadIdx.x;
      float4 v = ((const float4*)src)[i];
      ushort4 o;
      o.x = cvt_bf16(v.x); o.y = cvt_bf16(v.y); o.z = cvt_bf16(v.z); o.w = cvt_bf16(v.w);
      ((ushort4*)dst)[i] = o;
    }
    return;
  }
  // router: blocks [4096, 5120), one wave per token
  int gid = (bid - 4096) * blockDim.x + threadIdx.x;
  int t = gid >> 6;
  int lane = threadIdx.x & 63;
  if (t >= T_TOKENS) return;
  const float* xr = x + (size_t)t * DIM;
  float acc[NEXP];
#pragma unroll
  for (int e = 0; e < NEXP; ++e) acc[e] = 0.f;
  for (int d = lane; d < DIM; d += 64) {
    float xv = xr[d];
    const float* r = rw + (size_t)d * NEXP;
#pragma unroll
    for (int e = 0; e < NEXP; ++e) acc[e] += xv * r[e];
  }
#pragma unroll
  for (int e = 0; e < NEXP; ++e) {
#pragma unroll
    for (int off = 32; off > 0; off >>= 1) acc[e] += __shfl_xor(acc[e], off);
  }
  if (lane == 0) {
    float lg[NEXP], m = -1e30f;
#pragma unroll
    for (int e = 0; e < NEXP; ++e) { lg[e] = acc[e] + rb[e]; m = fmaxf(m, lg[e]); }
    float p[NEXP], Z = 0.f;
#pragma unroll
    for (int e = 0; e < NEXP; ++e) { p[e] = expf(lg[e] - m); Z += p[e]; }
    int i0 = 0;
#pragma unroll
    for (int e = 1; e < NEXP; ++e) if (p[e] > p[i0]) i0 = e;
    int i1 = (i0 == 0) ? 1 : 0;
#pragma unroll
    for (int e = 0; e < NEXP; ++e) if (e != i0 && p[e] > p[i1]) i1 = e;
    float q0 = p[i0] / Z, q1 = p[i1] / Z;
    float s = q0 + q1 + 1e-8f;
    tidx[t * 2] = i0; tidx[t * 2 + 1] = i1;
    tw[t * 2] = q0 / s; tw[t * 2 + 1] = q1 / s;
  }
}

// ---------------- scan: histogram + prefix + deterministic slot assignment -------------
__global__ __launch_bounds__(256) void scan_kernel(
    const int* __restrict__ tidx, int* __restrict__ offsets, int* __restrict__ ntiles_p,
    int* __restrict__ tlist, int* __restrict__ tslot) {
  __shared__ int lh[256][NEXP];
  __shared__ int offs[NEXP + 1];
  int t = threadIdx.x;
  int base = t * 32;
  int h[NEXP];
#pragma unroll
  for (int e = 0; e < NEXP; ++e) h[e] = 0;
#pragma unroll 1
  for (int a = 0; a < 32; ++a) {
    int e = tidx[base + a];
#pragma unroll
    for (int q = 0; q < NEXP; ++q) h[q] += (e == q);
  }
#pragma unroll
  for (int e = 0; e < NEXP; ++e) lh[t][e] = h[e];
  __syncthreads();
  if (t < NEXP) {
    int run = 0;
    for (int c = 0; c < 256; ++c) { int v = lh[c][t]; lh[c][t] = run; run += v; }
    offs[t + 1] = run;   // count[e]
  }
  __syncthreads();
  if (t == 0) {
    int s = 0, nt = 0;
    for (int e = 0; e < NEXP; ++e) {
      int cnt = offs[e + 1];
      offs[e] = s;
      offsets[e] = s;
      int m = (cnt + 127) >> 7;   // 128-row tiles
      for (int mt = 0; mt < m; ++mt) tlist[nt++] = (e << 8) | mt;
      s += cnt;
    }
    offsets[NEXP] = s;
    *ntiles_p = nt;   // <= 71
  }
  __syncthreads();
#pragma unroll 1
  for (int a = 0; a < 32; ++a) {
    int e = tidx[base + a];
    tslot[base + a] = offs[e] + lh[t][e];
    lh[t][e] += 1;
  }
}

// ---------------- gather x rows (fp32 -> bf16), atomic-free ----------------
__global__ void gather_kernel(const float* __restrict__ x, const int* __restrict__ tslot,
                              unsigned short* __restrict__ Xg) {
  int aid = (blockIdx.x * blockDim.x + threadIdx.x) >> 6;
  int lane = threadIdx.x & 63;
  if (aid >= NASSIGN) return;
  int t = aid >> 1;
  int slot = tslot[aid];
  const float4* xr = (const float4*)(x + (size_t)t * DIM);
  ushort4* dst = (ushort4*)(Xg + (size_t)slot * DIM);
#pragma unroll
  for (int i = 0; i < 4; ++i) {
    int idx = i * 64 + lane;
    float4 v = xr[idx];
    ushort4 o;
    o.x = cvt_bf16(v.x); o.y = cvt_bf16(v.y); o.z = cvt_bf16(v.z); o.w = cvt_bf16(v.w);
    dst[idx] = o;
  }
}

// ---------------- 128x128 grouped GEMM: 4 waves (2Mx2N), 4 blocks/CU, tr_read B -------
// R11-verified core. A: [slots][KTOT] bf16 K-major (ds_read_b128 + XOR swizzle).
// Bc: [E][KTOT][NN] bf16 natural K-major weights via ds_read_b64_tr_b16 subtiled LDS.
// Balanced contiguous XCD runs: XCD x owns q+(x<r) consecutive tlist entries.
#define COMPUTE_KK(KK)                                                                   \
  {                                                                                      \
    short4v lo[4], hi[4];                                                                \
    tr2<(KK) * 8192 + 0>(lo[0], hi[0], vb2);                                             \
    tr2<(KK) * 8192 + 128>(lo[1], hi[1], vb2);                                           \
    tr2<(KK) * 8192 + 256>(lo[2], hi[2], vb2);                                           \
    tr2<(KK) * 8192 + 384>(lo[3], hi[3], vb2);                                           \
    int cb = ((KK) * 64 + (l >> 4) * 16) ^ ((l & 7) << 4);                               \
    bf16x8 af[4];                                                                        \
    _Pragma("unroll") for (int i = 0; i < 4; ++i) {                                      \
      int row = wm * 64 + i * 16 + (l & 15);                                             \
      af[i] = *(const bf16x8*)((const char*)&As[0] + row * 128 + cb);                    \
    }                                                                                    \
    asm volatile("s_waitcnt lgkmcnt(0)" ::: "memory");                                   \
    __builtin_amdgcn_sched_barrier(0);                                                   \
    _Pragma("unroll") for (int j = 0; j < 4; ++j) {                                      \
      bf16x8 bfr = __builtin_bit_cast(                                                   \
          bf16x8, (short8v)__builtin_shufflevector(lo[j], hi[j], 0, 1, 2, 3, 4, 5, 6, 7)); \
      _Pragma("unroll") for (int i = 0; i < 4; ++i)                                      \
        acc[i][j] = __builtin_amdgcn_mfma_f32_16x16x32_bf16(af[i], bfr, acc[i][j], 0, 0, 0); \
    }                                                                                    \
  }

template <bool GELU, int KTOT, int NN, bool PARTIAL, int NSPLIT, int NCH, int MM>
__global__ __launch_bounds__(256, 4) void ffn_gemm128(
    const unsigned short* __restrict__ A, const unsigned short* __restrict__ Bc,
    const float* __restrict__ bias, void* __restrict__ OutP,
    const int* __restrict__ offsets, const int* __restrict__ ntiles_p,
    const int* __restrict__ tlist) {
  int gx = gridDim.x;
  int orig = blockIdx.y * gx + blockIdx.x;
  int xcd   = orig & 7;
  int local = orig >> 3;               // [0, gx*MM)
  int nc  = local / (NCH * MM);
  int rem = local - nc * (NCH * MM);
  int m   = rem / NCH;
  int nn  = rem - m * NCH;
  int xb  = nc * NCH + nn;

  int ntiles = *ntiles_p;
  int q = ntiles >> 3, r = ntiles & 7;
  int cnt = q + (xcd < r ? 1 : 0);
  if (m >= cnt) return;
  int yb = xcd * q + (xcd < r ? xcd : r) + m;   // contiguous balanced run

  int kh = 0;
  if (NSPLIT > 1) { kh = xb % NSPLIT; xb /= NSPLIT; }

  int ent = tlist[yb];
  int e = ent >> 8, mt = ent & 255;
  int off = offsets[e];
  int n_e = offsets[e + 1] - off;
  int row0 = off + mt * 128;
  if (mt * 128 >= n_e) return;
  int rows_valid = n_e - mt * 128; if (rows_valid > 128) rows_valid = 128;
  int n0 = xb * 128;
  constexpr int KSTEPS = KTOT / 64;
  int ks0 = KSTEPS / NSPLIT, krem = KSTEPS % NSPLIT;
  int ksteps = ks0 + (kh < krem ? 1 : 0);
  int kbase  = (kh * ks0 + (kh < krem ? kh : krem)) * 64;

  __shared__ unsigned short As[128 * 64];   // 16 KB
  __shared__ unsigned short Bs[64 * 128];   // 16 KB

  int tid = threadIdx.x, w = tid >> 6, l = tid & 63;
  int wm = w >> 1, wn = w & 1;

  f32x4 acc[4][4] = {};

  const unsigned short* Ab = A + (size_t)row0 * KTOT;
  const unsigned short* Bg = Bc + (size_t)e * KTOT * NN + n0;
  int srow = l >> 3;                     // A: row within 8-row group
  int scol = ((l & 7) ^ (l >> 3)) * 8;   // A: pre-swizzled source chunk (shorts)
  int kr   = (l >> 1) & 3;               // B: k row within 4-row subtile
  int ncol = ((l >> 3) << 4) + ((l & 1) << 3);   // B: n col (16B chunk)

  unsigned bsOff = (unsigned)(uintptr_t)(__attribute__((address_space(3))) unsigned short*)Bs;
  unsigned vb2 = bsOff + ((unsigned)(l >> 4) << 11) + ((unsigned)(l & 15) << 3)
               + ((unsigned)wn << 9);

#pragma unroll 1
  for (int ks = 0; ks < ksteps; ++ks) {
    int k0 = kbase + ks * 64;
#pragma unroll
    for (int i = 0; i < 4; ++i) {
      int R = w * 32 + i * 8;
      gload_lds16(Ab + (size_t)(R + srow) * KTOT + k0 + scol, &As[R * 64]);
      int kg = w * 4 + i;
      gload_lds16(Bg + (size_t)(k0 + kg * 4 + kr) * NN + ncol, &Bs[kg * 512]);
    }
    __syncthreads();
    COMPUTE_KK(0)
    COMPUTE_KK(1)
    __syncthreads();
  }

  int cr = (l >> 4) * 4, cc = l & 15;
#pragma unroll
  for (int i = 0; i < 4; ++i) {
#pragma unroll
    for (int rr = 0; rr < 4; ++rr) {
      int rl = wm * 64 + i * 16 + cr + rr;
      if (rl < rows_valid) {
#pragma unroll
        for (int j = 0; j < 4; ++j) {
          int col = n0 + wn * 64 + j * 16 + cc;
          unsigned short* Oh = (unsigned short*)OutP;
          if (PARTIAL) {
            Oh[((size_t)(kh * PADROWS) + row0 + rl) * NN + col] = cvt_bf16(acc[i][j][rr]);
          } else {
            float v = acc[i][j][rr] + bias[(size_t)e * NN + col];
            if (GELU) v = 0.5f * v * (1.0f + erff(v * 0.70710678118654752f));
            Oh[(size_t)(row0 + rl) * NN + col] = cvt_bf16(v);
          }
        }
      }
    }
  }
}

// ---------------- combine: out = x + sum_k w_k*(sum_kh EOp[kh][s_k] + b2[e_k]) ----------
__global__ void combine_kernel(const float* __restrict__ x, const unsigned short* __restrict__ EOp,
                               const int* __restrict__ tslot, const int* __restrict__ tidx,
                               const float* __restrict__ tw, const float* __restrict__ b2,
                               float* __restrict__ out) {
  int t = blockIdx.x;
  int s0 = tslot[t * 2], s1 = tslot[t * 2 + 1];
  int e0 = tidx[t * 2], e1 = tidx[t * 2 + 1];
  float w0 = tw[t * 2], w1 = tw[t * 2 + 1];
  int i = threadIdx.x;
  float4 xv = ((const float4*)(x + (size_t)t * DIM))[i];
  float4 b0 = ((const float4*)(b2 + (size_t)e0 * DIM))[i];
  float4 b1 = ((const float4*)(b2 + (size_t)e1 * DIM))[i];
  float sa[4] = {b0.x, b0.y, b0.z, b0.w};
  float sb[4] = {b1.x, b1.y, b1.z, b1.w};
#pragma unroll
  for (int kh = 0; kh < 2; ++kh) {
    ushort4 a = ((const ushort4*)(EOp + ((size_t)kh * PADROWS + s0) * DIM))[i];
    ushort4 c = ((const ushort4*)(EOp + ((size_t)kh * PADROWS + s1) * DIM))[i];
    sa[0] += b2f(a.x); sa[1] += b2f(a.y); sa[2] += b2f(a.z); sa[3] += b2f(a.w);
    sb[0] += b2f(c.x); sb[1] += b2f(c.y); sb[2] += b2f(c.z); sb[3] += b2f(c.w);
  }
  float4 o;
  o.x = xv.x + w0 * sa[0] + w1 * sb[0];
  o.y = xv.y + w0 * sa[1] + w1 * sb[1];
  o.z = xv.z + w0 * sa[2] + w1 * sb[2];
  o.w = xv.w + w0 * sa[3] + w1 * sb[3];
  ((float4*)(out + (size_t)t * DIM))[i] = o;
}

extern "C" void kernel_launch(void* const* d_in, const int* in_sizes, int n_in,
                              void* d_out, int out_size, void* d_ws, size_t ws_size,
                              hipStream_t stream) {
  const float* x        = (const float*)d_in[0];
  const float* router_w = (const float*)d_in[1];
  const float* router_b = (const float*)d_in[2];
  const float* w1       = (const float*)d_in[3];
  const float* b1       = (const float*)d_in[4];
  const float* w2       = (const float*)d_in[5];
  const float* b2       = (const float*)d_in[6];
  float* out = (float*)d_out;
  char* ws = (char*)d_ws;

  int*   offsets = (int*)(ws + 128);
  int*   ntilesp = (int*)(ws + 192);
  int*   tlist   = (int*)(ws + 256);
  int*   tidx    = (int*)(ws + 4096);
  float* tw      = (float*)(ws + 36864);
  int*   tslot   = (int*)(ws + 69632);
  // [Xg 17.3][H 69.2][W2c 67.1][W1c 67.1 | EOp(bf16 x2, 34.6, aliases W1c after GEMM1)]
  const size_t XG_OFF  = 1u << 20;
  const size_t XG_B    = (size_t)PADROWS * DIM * 2;
  const size_t H_OFF   = XG_OFF + XG_B;
  const size_t H_B     = (size_t)PADROWS * FDIM * 2;
  const size_t W2C_OFF = H_OFF + H_B;
  const size_t WC_B    = (size_t)NEXP * DIM * FDIM * 2;
  const size_t W1C_OFF = W2C_OFF + WC_B;
  const size_t EOP_OFF = W1C_OFF;                          // alias (W1c dead after GEMM1)
  unsigned short* Xg  = (unsigned short*)(ws + XG_OFF);
  unsigned short* H   = (unsigned short*)(ws + H_OFF);
  unsigned short* W2c = (unsigned short*)(ws + W2C_OFF);
  unsigned short* W1c = (unsigned short*)(ws + W1C_OFF);
  unsigned short* EOp = (unsigned short*)(ws + EOP_OFF);   // [2][PADROWS][DIM] bf16

  // fused: convert W1 | convert W2 | router (atomic-free, block-contiguous converts)
  prep_kernel<<<5120, 256, 0, stream>>>(w1, w2, W1c, W2c, x, router_w, router_b, tidx, tw);
  scan_kernel<<<1, 256, 0, stream>>>(tidx, offsets, ntilesp, tlist, tslot);
  gather_kernel<<<NASSIGN / 4, 256, 0, stream>>>(x, tslot, Xg);
  // H = gelu(Xg @ W1 + b1): 128x128 tiles, x = 32 n-tiles, y = 72 (8 XCD x MM=9)
  ffn_gemm128<true, DIM, FDIM, false, 1, 8, 9><<<dim3(FDIM / 128, 72), 256, 0, stream>>>(
      Xg, W1c, b1, (void*)H, offsets, ntilesp, tlist);
  // EOp[kh] = H @ W2 (split-K x2 bf16 partials, bias deferred): x = 8 n-tiles x 2 kh
  ffn_gemm128<false, FDIM, DIM, true, 2, 4, 9><<<dim3(DIM / 128 * 2, 72), 256, 0, stream>>>(
      H, W2c, b2, (void*)EOp, offsets, ntilesp, tlist);
  combine_kernel<<<T_TOKENS, 256, 0, stream>>>(x, EOp, tslot, tidx, tw, b2, out);
}